// Round 2
// baseline (5756.883 us; speedup 1.0000x reference)
//
#include <hip/hip_runtime.h>
#include <hip/hip_bf16.h>

#define HID 512
#define TM 128
#define TN 128
#define TK 16

// ---------------- degree / norm ----------------

__global__ __launch_bounds__(256) void k_deg(const int* __restrict__ ei, int E, int* __restrict__ deg) {
    int e = blockIdx.x * 256 + threadIdx.x;
    if (e < E) atomicAdd(&deg[ei[E + e]], 1);
}

__global__ __launch_bounds__(256) void k_dinv(float* __restrict__ degf, int N) {
    int n = blockIdx.x * 256 + threadIdx.x;
    if (n < N) {
        int c = ((const int*)degf)[n];
        degf[n] = (c > 0) ? rsqrtf((float)c) : 0.0f;  // max(deg,1)==deg when deg>0
    }
}

__global__ __launch_bounds__(256) void k_norm(const int* __restrict__ ei, int E,
                                              const float* __restrict__ dinv, float* __restrict__ norm) {
    int e = blockIdx.x * 256 + threadIdx.x;
    if (e < E) norm[e] = dinv[ei[e]] * dinv[ei[E + e]];
}

// ---------------- fp32 GEMM: C[M,512] (+)= A[M,512] @ B[512,512] ----------------

template<int ACCUM>
__global__ __launch_bounds__(256) void k_gemm(const float* __restrict__ A, const float* __restrict__ B,
                                              float* __restrict__ C, int M) {
    __shared__ float As[TK][TM];   // transposed A tile: As[k][m]
    __shared__ float Bs[TK][TN];
    const int K = HID, N = HID;
    int bm = blockIdx.x * TM;
    int bn = blockIdx.y * TN;
    int tid = threadIdx.x;
    int rm = tid >> 4, cn = tid & 15;          // 16x16 thread grid, 8x8 micro-tile
    int a_row = tid >> 1;                       // 0..127
    int a_k8  = (tid & 1) * 8;                  // 0 or 8
    int b_k   = tid >> 4;                       // 0..15
    int b_n8  = (tid & 15) * 8;                 // 0..120

    float acc[8][8] = {};

    for (int k0 = 0; k0 < K; k0 += TK) {
        float4 av0 = {0,0,0,0}, av1 = {0,0,0,0};
        int gr = bm + a_row;
        if (gr < M) {
            const float* ap = &A[(size_t)gr * K + k0 + a_k8];
            av0 = *(const float4*)ap;
            av1 = *(const float4*)(ap + 4);
        }
        As[a_k8+0][a_row] = av0.x; As[a_k8+1][a_row] = av0.y;
        As[a_k8+2][a_row] = av0.z; As[a_k8+3][a_row] = av0.w;
        As[a_k8+4][a_row] = av1.x; As[a_k8+5][a_row] = av1.y;
        As[a_k8+6][a_row] = av1.z; As[a_k8+7][a_row] = av1.w;

        const float* bp = &B[(size_t)(k0 + b_k) * N + bn + b_n8];
        *(float4*)&Bs[b_k][b_n8]     = *(const float4*)bp;
        *(float4*)&Bs[b_k][b_n8 + 4] = *(const float4*)(bp + 4);
        __syncthreads();

        #pragma unroll
        for (int k = 0; k < TK; ++k) {
            float4 a0 = *(const float4*)&As[k][rm*8];
            float4 a1 = *(const float4*)&As[k][rm*8 + 4];
            float4 b0 = *(const float4*)&Bs[k][cn*8];
            float4 b1 = *(const float4*)&Bs[k][cn*8 + 4];
            float a[8] = {a0.x,a0.y,a0.z,a0.w,a1.x,a1.y,a1.z,a1.w};
            float b[8] = {b0.x,b0.y,b0.z,b0.w,b1.x,b1.y,b1.z,b1.w};
            #pragma unroll
            for (int i = 0; i < 8; ++i)
                #pragma unroll
                for (int j = 0; j < 8; ++j)
                    acc[i][j] = fmaf(a[i], b[j], acc[i][j]);
        }
        __syncthreads();
    }

    #pragma unroll
    for (int i = 0; i < 8; ++i) {
        int gr = bm + rm*8 + i;
        if (gr < M) {
            float* cp = &C[(size_t)gr * N + bn + cn*8];
            if (ACCUM) {
                float4 c0 = *(float4*)cp, c1 = *(float4*)(cp + 4);
                c0.x += acc[i][0]; c0.y += acc[i][1]; c0.z += acc[i][2]; c0.w += acc[i][3];
                c1.x += acc[i][4]; c1.y += acc[i][5]; c1.z += acc[i][6]; c1.w += acc[i][7];
                *(float4*)cp = c0; *(float4*)(cp + 4) = c1;
            } else {
                float4 c0 = {acc[i][0], acc[i][1], acc[i][2], acc[i][3]};
                float4 c1 = {acc[i][4], acc[i][5], acc[i][6], acc[i][7]};
                *(float4*)cp = c0; *(float4*)(cp + 4) = c1;
            }
        }
    }
}

// ---------------- edge scatter: agg[dst] += xw[src] * norm ----------------

__global__ __launch_bounds__(256) void k_scatter(const float* __restrict__ xw, const int* __restrict__ ei,
                                                 const float* __restrict__ norm, float* __restrict__ agg, int E) {
    int wave = threadIdx.x >> 6, lane = threadIdx.x & 63;
    int e = blockIdx.x * 4 + wave;
    if (e >= E) return;
    int s = ei[e];
    int d = ei[E + e];
    float w = norm[e];
    const float* xp = &xw[(size_t)s * HID + lane * 4];
    float*       ap = &agg[(size_t)d * HID + lane * 4];
    float4 v0 = *(const float4*)xp;
    float4 v1 = *(const float4*)(xp + 256);
    unsafeAtomicAdd(ap + 0,   v0.x * w);
    unsafeAtomicAdd(ap + 1,   v0.y * w);
    unsafeAtomicAdd(ap + 2,   v0.z * w);
    unsafeAtomicAdd(ap + 3,   v0.w * w);
    unsafeAtomicAdd(ap + 256, v1.x * w);
    unsafeAtomicAdd(ap + 257, v1.y * w);
    unsafeAtomicAdd(ap + 258, v1.z * w);
    unsafeAtomicAdd(ap + 259, v1.w * w);
}

// ---------------- LayerNorm (in-place, one wave per row) ----------------

__global__ __launch_bounds__(256) void k_ln(float* __restrict__ x, const float* __restrict__ bias,
                                            const float* __restrict__ gamma, const float* __restrict__ beta, int N) {
    int wave = threadIdx.x >> 6, lane = threadIdx.x & 63;
    int row = blockIdx.x * 4 + wave;
    if (row >= N) return;
    float* xr = x + (size_t)row * HID;
    int c0 = lane * 8;
    float4 p0 = *(const float4*)&xr[c0];
    float4 p1 = *(const float4*)&xr[c0 + 4];
    float4 b0 = *(const float4*)&bias[c0];
    float4 b1 = *(const float4*)&bias[c0 + 4];
    float v[8] = {p0.x+b0.x, p0.y+b0.y, p0.z+b0.z, p0.w+b0.w,
                  p1.x+b1.x, p1.y+b1.y, p1.z+b1.z, p1.w+b1.w};
    float s1 = 0.f, s2 = 0.f;
    #pragma unroll
    for (int j = 0; j < 8; ++j) { s1 += v[j]; s2 += v[j]*v[j]; }
    #pragma unroll
    for (int m = 1; m < 64; m <<= 1) { s1 += __shfl_xor(s1, m); s2 += __shfl_xor(s2, m); }
    float mu  = s1 * (1.0f/512.0f);
    float var = fmaxf(s2 * (1.0f/512.0f) - mu*mu, 0.0f);
    float r   = rsqrtf(var + 1e-5f);
    float4 g0 = *(const float4*)&gamma[c0];
    float4 g1 = *(const float4*)&gamma[c0 + 4];
    float4 e0 = *(const float4*)&beta[c0];
    float4 e1 = *(const float4*)&beta[c0 + 4];
    float g[8] = {g0.x,g0.y,g0.z,g0.w,g1.x,g1.y,g1.z,g1.w};
    float bb[8] = {e0.x,e0.y,e0.z,e0.w,e1.x,e1.y,e1.z,e1.w};
    float o[8];
    #pragma unroll
    for (int j = 0; j < 8; ++j) o[j] = (v[j]-mu)*r*g[j] + bb[j];
    float4 q0 = {o[0],o[1],o[2],o[3]}, q1 = {o[4],o[5],o[6],o[7]};
    *(float4*)&xr[c0]     = q0;
    *(float4*)&xr[c0 + 4] = q1;
}

// ---------------- gate blend: hc = sig(acc+bg)*hn + (1-sig)*hc ----------------

__global__ __launch_bounds__(256) void k_blend(const float* __restrict__ acc, const float* __restrict__ bg,
                                               const float* __restrict__ hn, float* __restrict__ hc, int total4) {
    int i = blockIdx.x * 256 + threadIdx.x;
    if (i >= total4) return;
    int col4 = (i & 127) * 4;  // 128 float4 per row
    float4 a = ((const float4*)acc)[i];
    float4 b = *(const float4*)&bg[col4];
    float4 n = ((const float4*)hn)[i];
    float4 h = ((float4*)hc)[i];
    float gx = 1.0f / (1.0f + __expf(-(a.x + b.x)));
    float gy = 1.0f / (1.0f + __expf(-(a.y + b.y)));
    float gz = 1.0f / (1.0f + __expf(-(a.z + b.z)));
    float gw = 1.0f / (1.0f + __expf(-(a.w + b.w)));
    h.x = gx * n.x + (1.0f - gx) * h.x;
    h.y = gy * n.y + (1.0f - gy) * h.y;
    h.z = gz * n.z + (1.0f - gz) * h.z;
    h.w = gw * n.w + (1.0f - gw) * h.w;
    ((float4*)hc)[i] = h;
}

// ---------------- final: out = tanh(hc) + rw * h_orig ----------------

__global__ __launch_bounds__(256) void k_final(const float* __restrict__ hc, const float* __restrict__ h0,
                                               const float* __restrict__ rw_p, float* __restrict__ out, int total4) {
    int i = blockIdx.x * 256 + threadIdx.x;
    if (i >= total4) return;
    float rw = *rw_p;
    float4 h = ((const float4*)hc)[i];
    float4 o = ((const float4*)h0)[i];
    float4 r;
    r.x = tanhf(h.x) + rw * o.x;
    r.y = tanhf(h.y) + rw * o.y;
    r.z = tanhf(h.z) + rw * o.z;
    r.w = tanhf(h.w) + rw * o.w;
    ((float4*)out)[i] = r;
}

// ---------------- launch ----------------

extern "C" void kernel_launch(void* const* d_in, const int* in_sizes, int n_in,
                              void* d_out, int out_size, void* d_ws, size_t ws_size,
                              hipStream_t stream) {
    const float* h_in   = (const float*)d_in[1];
    const int*   ei     = (const int*)d_in[2];      // harness delivers integers as int32
    const float* W_gcn  = (const float*)d_in[3];
    const float* b_gcn  = (const float*)d_in[4];
    const float* ln_g   = (const float*)d_in[5];
    const float* ln_b   = (const float*)d_in[6];
    const float* W_gate = (const float*)d_in[7];
    const float* b_gate = (const float*)d_in[8];
    const float* rw     = (const float*)d_in[9];
    int N = in_sizes[1] / HID;
    int E = in_sizes[2] / 2;
    float* out = (float*)d_out;

    char* ws = (char*)d_ws;
    size_t nb = (size_t)N * HID * sizeof(float);
    float* bufA = (float*)ws;                        // xw / gate accumulator
    float* bufB = (float*)(ws + nb);                 // current h
    float* dinv = (float*)(ws + 2*nb);               // deg -> dinv (in place)
    float* norm = (float*)(ws + 2*nb + (((size_t)N*4 + 255)/256)*256);

    // degree, dinv, per-edge norm
    hipMemsetAsync(dinv, 0, (size_t)N * 4, stream);
    k_deg<<<(E + 255)/256, 256, 0, stream>>>(ei, E, (int*)dinv);
    k_dinv<<<(N + 255)/256, 256, 0, stream>>>(dinv, N);
    k_norm<<<(E + 255)/256, 256, 0, stream>>>(ei, E, dinv, norm);

    dim3 gg((N + TM - 1)/TM, HID/TN);
    int total4 = N * HID / 4;

    // layer 0: h = LN(scatter(h_in @ W0) + b0)
    k_gemm<0><<<gg, 256, 0, stream>>>(h_in, W_gcn, bufA, N);
    hipMemsetAsync(bufB, 0, nb, stream);
    k_scatter<<<(E + 3)/4, 256, 0, stream>>>(bufA, ei, norm, bufB, E);
    k_ln<<<(N + 3)/4, 256, 0, stream>>>(bufB, b_gcn, ln_g, ln_b, N);

    // layers 1,2 with gate
    for (int i = 1; i <= 2; ++i) {
        k_gemm<0><<<gg, 256, 0, stream>>>(bufB, W_gcn + (size_t)i*HID*HID, bufA, N);
        hipMemsetAsync(out, 0, nb, stream);
        k_scatter<<<(E + 3)/4, 256, 0, stream>>>(bufA, ei, norm, out, E);
        k_ln<<<(N + 3)/4, 256, 0, stream>>>(out, b_gcn + i*HID, ln_g + i*HID, ln_b + i*HID, N);
        // gate = sigmoid(h @ Wg[:512] + h_new @ Wg[512:] + bg)
        k_gemm<0><<<gg, 256, 0, stream>>>(bufB, W_gate, bufA, N);
        k_gemm<1><<<gg, 256, 0, stream>>>(out, W_gate + (size_t)HID*HID, bufA, N);
        k_blend<<<(total4 + 255)/256, 256, 0, stream>>>(bufA, b_gate, out, bufB, total4);
    }

    // out = tanh(h) + rw * h_orig
    k_final<<<(total4 + 255)/256, 256, 0, stream>>>(bufB, h_in, rw, out, total4);
}

// Round 3
// 2651.217 us; speedup vs baseline: 2.1714x; 2.1714x over previous
//
#include <hip/hip_runtime.h>
#include <hip/hip_bf16.h>

#define HID 512
#define TM 128
#define TN 128
#define TK 16

// ---------------- degree ----------------

__global__ __launch_bounds__(256) void k_deg(const int* __restrict__ ei, int E, int* __restrict__ deg) {
    int e = blockIdx.x * 256 + threadIdx.x;
    if (e < E) atomicAdd(&deg[ei[E + e]], 1);
}

__global__ __launch_bounds__(256) void k_dinv(const int* __restrict__ deg, float* __restrict__ dinv, int N) {
    int n = blockIdx.x * 256 + threadIdx.x;
    if (n < N) {
        int c = deg[n];
        dinv[n] = (c > 0) ? rsqrtf((float)c) : 0.0f;
    }
}

// ---------------- exclusive scan of deg -> rowptr, cursor ----------------
// scan1: per-block inclusive scan of deg into rowptr[i+1]; block total into bsum
__global__ __launch_bounds__(256) void k_scan1(const int* __restrict__ deg, int N,
                                               int* __restrict__ rowptr, int* __restrict__ bsum) {
    int i = blockIdx.x * 256 + threadIdx.x;
    int v = (i < N) ? deg[i] : 0;
    int lane = threadIdx.x & 63, w = threadIdx.x >> 6;
    int s = v;
    #pragma unroll
    for (int m = 1; m < 64; m <<= 1) { int t = __shfl_up(s, m); if (lane >= m) s += t; }
    __shared__ int wsum[4];
    if (lane == 63) wsum[w] = s;
    __syncthreads();
    #pragma unroll
    for (int j = 0; j < 4; ++j) if (j < w) s += wsum[j];
    if (i < N) rowptr[i + 1] = s;
    if (threadIdx.x == 255) bsum[blockIdx.x] = s;
}

// scan2: single block exclusive scan of bsum (nb <= 256)
__global__ __launch_bounds__(256) void k_scan2(int* __restrict__ bsum, int nb) {
    int tid = threadIdx.x;
    int v = (tid < nb) ? bsum[tid] : 0;
    int lane = tid & 63, w = tid >> 6;
    int s = v;
    #pragma unroll
    for (int m = 1; m < 64; m <<= 1) { int t = __shfl_up(s, m); if (lane >= m) s += t; }
    __shared__ int wsum[4];
    if (lane == 63) wsum[w] = s;
    __syncthreads();
    #pragma unroll
    for (int j = 0; j < 4; ++j) if (j < w) s += wsum[j];
    if (tid < nb) bsum[tid] = s - v;   // exclusive
}

// scan3: add block offsets; emit rowptr (global) and cursor (= exclusive prefix)
__global__ __launch_bounds__(256) void k_scan3(const int* __restrict__ deg, const int* __restrict__ bsum,
                                               int N, int* __restrict__ rowptr, int* __restrict__ cursor) {
    int i = blockIdx.x * 256 + threadIdx.x;
    if (i == 0) rowptr[0] = 0;
    if (i < N) {
        int inc = rowptr[i + 1] + bsum[blockIdx.x];
        rowptr[i + 1] = inc;
        cursor[i] = inc - deg[i];
    }
}

// fill CSR: esrc[slot]=src, escale[slot]=dinv[src]
__global__ __launch_bounds__(256) void k_fill(const int* __restrict__ ei, int E,
                                              const float* __restrict__ dinv, int* __restrict__ cursor,
                                              int* __restrict__ esrc, float* __restrict__ escale) {
    int e = blockIdx.x * 256 + threadIdx.x;
    if (e < E) {
        int s = ei[e], d = ei[E + e];
        int slot = atomicAdd(&cursor[d], 1);
        esrc[slot] = s;
        escale[slot] = dinv[s];
    }
}

// ---------------- fp32 GEMM: C[M,512] (+)= A[M,512] @ B[512,512] ----------------

template<int ACCUM>
__global__ __launch_bounds__(256) void k_gemm(const float* __restrict__ A, const float* __restrict__ B,
                                              float* __restrict__ C, int M) {
    __shared__ float As[TK][TM];   // transposed A tile: As[k][m]
    __shared__ float Bs[TK][TN];
    const int K = HID, N = HID;
    int bm = blockIdx.x * TM;
    int bn = blockIdx.y * TN;
    int tid = threadIdx.x;
    int rm = tid >> 4, cn = tid & 15;          // 16x16 thread grid, 8x8 micro-tile
    int a_row = tid >> 1;                       // 0..127
    int a_k8  = (tid & 1) * 8;                  // 0 or 8
    int b_k   = tid >> 4;                       // 0..15
    int b_n8  = (tid & 15) * 8;                 // 0..120

    float acc[8][8] = {};

    for (int k0 = 0; k0 < K; k0 += TK) {
        float4 av0 = {0,0,0,0}, av1 = {0,0,0,0};
        int gr = bm + a_row;
        if (gr < M) {
            const float* ap = &A[(size_t)gr * K + k0 + a_k8];
            av0 = *(const float4*)ap;
            av1 = *(const float4*)(ap + 4);
        }
        As[a_k8+0][a_row] = av0.x; As[a_k8+1][a_row] = av0.y;
        As[a_k8+2][a_row] = av0.z; As[a_k8+3][a_row] = av0.w;
        As[a_k8+4][a_row] = av1.x; As[a_k8+5][a_row] = av1.y;
        As[a_k8+6][a_row] = av1.z; As[a_k8+7][a_row] = av1.w;

        const float* bp = &B[(size_t)(k0 + b_k) * N + bn + b_n8];
        *(float4*)&Bs[b_k][b_n8]     = *(const float4*)bp;
        *(float4*)&Bs[b_k][b_n8 + 4] = *(const float4*)(bp + 4);
        __syncthreads();

        #pragma unroll
        for (int k = 0; k < TK; ++k) {
            float4 a0 = *(const float4*)&As[k][rm*8];
            float4 a1 = *(const float4*)&As[k][rm*8 + 4];
            float4 b0 = *(const float4*)&Bs[k][cn*8];
            float4 b1 = *(const float4*)&Bs[k][cn*8 + 4];
            float a[8] = {a0.x,a0.y,a0.z,a0.w,a1.x,a1.y,a1.z,a1.w};
            float b[8] = {b0.x,b0.y,b0.z,b0.w,b1.x,b1.y,b1.z,b1.w};
            #pragma unroll
            for (int i = 0; i < 8; ++i)
                #pragma unroll
                for (int j = 0; j < 8; ++j)
                    acc[i][j] = fmaf(a[i], b[j], acc[i][j]);
        }
        __syncthreads();
    }

    #pragma unroll
    for (int i = 0; i < 8; ++i) {
        int gr = bm + rm*8 + i;
        if (gr < M) {
            float* cp = &C[(size_t)gr * N + bn + cn*8];
            if (ACCUM) {
                float4 c0 = *(float4*)cp, c1 = *(float4*)(cp + 4);
                c0.x += acc[i][0]; c0.y += acc[i][1]; c0.z += acc[i][2]; c0.w += acc[i][3];
                c1.x += acc[i][4]; c1.y += acc[i][5]; c1.z += acc[i][6]; c1.w += acc[i][7];
                *(float4*)cp = c0; *(float4*)(cp + 4) = c1;
            } else {
                float4 c0 = {acc[i][0], acc[i][1], acc[i][2], acc[i][3]};
                float4 c1 = {acc[i][4], acc[i][5], acc[i][6], acc[i][7]};
                *(float4*)cp = c0; *(float4*)(cp + 4) = c1;
            }
        }
    }
}

// ---------------- fused gather + bias + LayerNorm: one wave per dst row ----------------

__global__ __launch_bounds__(256) void k_gather(const float* __restrict__ xw, const int* __restrict__ rowptr,
                                                const int* __restrict__ esrc, const float* __restrict__ escale,
                                                const float* __restrict__ dinv, const float* __restrict__ bias,
                                                const float* __restrict__ gamma, const float* __restrict__ beta,
                                                float* __restrict__ out, int N) {
    int wave = threadIdx.x >> 6, lane = threadIdx.x & 63;
    int n = blockIdx.x * 4 + wave;
    if (n >= N) return;
    int beg = rowptr[n], end = rowptr[n + 1];
    int c0 = lane * 8;
    float acc[8] = {};
    for (int j = beg; j < end; ++j) {
        int s = esrc[j];
        float w = escale[j];
        const float* xp = &xw[(size_t)s * HID + c0];
        float4 v0 = *(const float4*)xp;
        float4 v1 = *(const float4*)(xp + 4);
        acc[0] = fmaf(w, v0.x, acc[0]); acc[1] = fmaf(w, v0.y, acc[1]);
        acc[2] = fmaf(w, v0.z, acc[2]); acc[3] = fmaf(w, v0.w, acc[3]);
        acc[4] = fmaf(w, v1.x, acc[4]); acc[5] = fmaf(w, v1.y, acc[5]);
        acc[6] = fmaf(w, v1.z, acc[6]); acc[7] = fmaf(w, v1.w, acc[7]);
    }
    float dn = dinv[n];
    float4 b0 = *(const float4*)&bias[c0];
    float4 b1 = *(const float4*)&bias[c0 + 4];
    float bb[8] = {b0.x,b0.y,b0.z,b0.w,b1.x,b1.y,b1.z,b1.w};
    float v[8];
    #pragma unroll
    for (int j = 0; j < 8; ++j) v[j] = fmaf(acc[j], dn, bb[j]);
    float s1 = 0.f, s2 = 0.f;
    #pragma unroll
    for (int j = 0; j < 8; ++j) { s1 += v[j]; s2 += v[j]*v[j]; }
    #pragma unroll
    for (int m = 1; m < 64; m <<= 1) { s1 += __shfl_xor(s1, m); s2 += __shfl_xor(s2, m); }
    float mu  = s1 * (1.0f/512.0f);
    float var = fmaxf(s2 * (1.0f/512.0f) - mu*mu, 0.0f);
    float r   = rsqrtf(var + 1e-5f);
    float4 g0 = *(const float4*)&gamma[c0];
    float4 g1 = *(const float4*)&gamma[c0 + 4];
    float4 e0 = *(const float4*)&beta[c0];
    float4 e1 = *(const float4*)&beta[c0 + 4];
    float g[8]  = {g0.x,g0.y,g0.z,g0.w,g1.x,g1.y,g1.z,g1.w};
    float bt[8] = {e0.x,e0.y,e0.z,e0.w,e1.x,e1.y,e1.z,e1.w};
    float o[8];
    #pragma unroll
    for (int j = 0; j < 8; ++j) o[j] = (v[j]-mu)*r*g[j] + bt[j];
    float* xr = out + (size_t)n * HID;
    float4 q0 = {o[0],o[1],o[2],o[3]}, q1 = {o[4],o[5],o[6],o[7]};
    *(float4*)&xr[c0]     = q0;
    *(float4*)&xr[c0 + 4] = q1;
}

// ---------------- gate blend: hc = sig(acc+bg)*hn + (1-sig)*hc ----------------

__global__ __launch_bounds__(256) void k_blend(const float* __restrict__ acc, const float* __restrict__ bg,
                                               const float* __restrict__ hn, float* __restrict__ hc, int total4) {
    int i = blockIdx.x * 256 + threadIdx.x;
    if (i >= total4) return;
    int col4 = (i & 127) * 4;  // 128 float4 per row
    float4 a = ((const float4*)acc)[i];
    float4 b = *(const float4*)&bg[col4];
    float4 n = ((const float4*)hn)[i];
    float4 h = ((float4*)hc)[i];
    float gx = 1.0f / (1.0f + __expf(-(a.x + b.x)));
    float gy = 1.0f / (1.0f + __expf(-(a.y + b.y)));
    float gz = 1.0f / (1.0f + __expf(-(a.z + b.z)));
    float gw = 1.0f / (1.0f + __expf(-(a.w + b.w)));
    h.x = gx * n.x + (1.0f - gx) * h.x;
    h.y = gy * n.y + (1.0f - gy) * h.y;
    h.z = gz * n.z + (1.0f - gz) * h.z;
    h.w = gw * n.w + (1.0f - gw) * h.w;
    ((float4*)hc)[i] = h;
}

// ---------------- final: out = tanh(hc) + rw * h_orig ----------------

__global__ __launch_bounds__(256) void k_final(const float* __restrict__ hc, const float* __restrict__ h0,
                                               const float* __restrict__ rw_p, float* __restrict__ out, int total4) {
    int i = blockIdx.x * 256 + threadIdx.x;
    if (i >= total4) return;
    float rw = *rw_p;
    float4 h = ((const float4*)hc)[i];
    float4 o = ((const float4*)h0)[i];
    float4 r;
    r.x = tanhf(h.x) + rw * o.x;
    r.y = tanhf(h.y) + rw * o.y;
    r.z = tanhf(h.z) + rw * o.z;
    r.w = tanhf(h.w) + rw * o.w;
    ((float4*)out)[i] = r;
}

// ---------------- launch ----------------

extern "C" void kernel_launch(void* const* d_in, const int* in_sizes, int n_in,
                              void* d_out, int out_size, void* d_ws, size_t ws_size,
                              hipStream_t stream) {
    const float* h_in   = (const float*)d_in[1];
    const int*   ei     = (const int*)d_in[2];
    const float* W_gcn  = (const float*)d_in[3];
    const float* b_gcn  = (const float*)d_in[4];
    const float* ln_g   = (const float*)d_in[5];
    const float* ln_b   = (const float*)d_in[6];
    const float* W_gate = (const float*)d_in[7];
    const float* b_gate = (const float*)d_in[8];
    const float* rw     = (const float*)d_in[9];
    int N = in_sizes[1] / HID;
    int E = in_sizes[2] / 2;
    float* out = (float*)d_out;

    char* ws = (char*)d_ws;
    size_t nb = (size_t)N * HID * sizeof(float);
    size_t off = 0;
    auto alloc = [&](size_t bytes) { void* p = ws + off; off += (bytes + 255) & ~(size_t)255; return p; };
    float* bufA   = (float*)alloc(nb);            // xw / gate accumulator
    float* bufB   = (float*)alloc(nb);            // current h
    int*   deg    = (int*)  alloc((size_t)N * 4);
    float* dinv   = (float*)alloc((size_t)N * 4);
    int*   rowptr = (int*)  alloc((size_t)(N + 1) * 4);
    int*   cursor = (int*)  alloc((size_t)N * 4);
    int*   bsum   = (int*)  alloc(1024);
    int*   esrc   = (int*)  alloc((size_t)E * 4);
    float* escale = (float*)alloc((size_t)E * 4);

    int NB = (N + 255) / 256;

    // CSR build: deg -> dinv -> rowptr/cursor -> fill
    hipMemsetAsync(deg, 0, (size_t)N * 4, stream);
    k_deg  <<<(E + 255)/256, 256, 0, stream>>>(ei, E, deg);
    k_dinv <<<NB, 256, 0, stream>>>(deg, dinv, N);
    k_scan1<<<NB, 256, 0, stream>>>(deg, N, rowptr, bsum);
    k_scan2<<<1,  256, 0, stream>>>(bsum, NB);
    k_scan3<<<NB, 256, 0, stream>>>(deg, bsum, N, rowptr, cursor);
    k_fill <<<(E + 255)/256, 256, 0, stream>>>(ei, E, dinv, cursor, esrc, escale);

    dim3 gg((N + TM - 1)/TM, HID/TN);
    int total4 = N * HID / 4;
    int NG = (N + 3) / 4;

    // layer 0: h = LN(gather(h_in @ W0) + b0)
    k_gemm<0><<<gg, 256, 0, stream>>>(h_in, W_gcn, bufA, N);
    k_gather<<<NG, 256, 0, stream>>>(bufA, rowptr, esrc, escale, dinv, b_gcn, ln_g, ln_b, bufB, N);

    // layers 1,2 with gate
    for (int i = 1; i <= 2; ++i) {
        k_gemm<0><<<gg, 256, 0, stream>>>(bufB, W_gcn + (size_t)i*HID*HID, bufA, N);
        k_gather<<<NG, 256, 0, stream>>>(bufA, rowptr, esrc, escale, dinv,
                                         b_gcn + i*HID, ln_g + i*HID, ln_b + i*HID, out, N);
        // gate = sigmoid(h @ Wg[:512] + h_new @ Wg[512:] + bg)
        k_gemm<0><<<gg, 256, 0, stream>>>(bufB, W_gate, bufA, N);
        k_gemm<1><<<gg, 256, 0, stream>>>(out, W_gate + (size_t)HID*HID, bufA, N);
        k_blend<<<(total4 + 255)/256, 256, 0, stream>>>(bufA, b_gate, out, bufB, total4);
    }

    // out = tanh(h) + rw * h_orig
    k_final<<<(total4 + 255)/256, 256, 0, stream>>>(bufB, h_in, rw, out, total4);
}

// Round 4
// 1400.529 us; speedup vs baseline: 4.1105x; 1.8930x over previous
//
#include <hip/hip_runtime.h>
#include <hip/hip_bf16.h>

#define HID 512

typedef __attribute__((ext_vector_type(8))) short bf16x8;
typedef __attribute__((ext_vector_type(4))) float f32x4;

__device__ inline unsigned short f2bf(float x) {
    __hip_bfloat16 b = __float2bfloat16(x);
    return *reinterpret_cast<unsigned short*>(&b);
}
__device__ inline float bf_lo(unsigned int u) { return __uint_as_float(u << 16); }
__device__ inline float bf_hi(unsigned int u) { return __uint_as_float(u & 0xffff0000u); }
__device__ inline float bf2f(unsigned short u) { return __uint_as_float(((unsigned int)u) << 16); }

// ---------------- degree / CSR build ----------------

__global__ __launch_bounds__(256) void k_deg(const int* __restrict__ ei, int E, int* __restrict__ deg) {
    int e = blockIdx.x * 256 + threadIdx.x;
    if (e < E) atomicAdd(&deg[ei[E + e]], 1);
}

__global__ __launch_bounds__(256) void k_dinv(const int* __restrict__ deg, float* __restrict__ dinv, int N) {
    int n = blockIdx.x * 256 + threadIdx.x;
    if (n < N) {
        int c = deg[n];
        dinv[n] = (c > 0) ? rsqrtf((float)c) : 0.0f;
    }
}

__global__ __launch_bounds__(256) void k_scan1(const int* __restrict__ deg, int N,
                                               int* __restrict__ rowptr, int* __restrict__ bsum) {
    int i = blockIdx.x * 256 + threadIdx.x;
    int v = (i < N) ? deg[i] : 0;
    int lane = threadIdx.x & 63, w = threadIdx.x >> 6;
    int s = v;
    #pragma unroll
    for (int m = 1; m < 64; m <<= 1) { int t = __shfl_up(s, m); if (lane >= m) s += t; }
    __shared__ int wsum[4];
    if (lane == 63) wsum[w] = s;
    __syncthreads();
    #pragma unroll
    for (int j = 0; j < 4; ++j) if (j < w) s += wsum[j];
    if (i < N) rowptr[i + 1] = s;
    if (threadIdx.x == 255) bsum[blockIdx.x] = s;
}

__global__ __launch_bounds__(256) void k_scan2(int* __restrict__ bsum, int nb) {
    int tid = threadIdx.x;
    int v = (tid < nb) ? bsum[tid] : 0;
    int lane = tid & 63, w = tid >> 6;
    int s = v;
    #pragma unroll
    for (int m = 1; m < 64; m <<= 1) { int t = __shfl_up(s, m); if (lane >= m) s += t; }
    __shared__ int wsum[4];
    if (lane == 63) wsum[w] = s;
    __syncthreads();
    #pragma unroll
    for (int j = 0; j < 4; ++j) if (j < w) s += wsum[j];
    if (tid < nb) bsum[tid] = s - v;
}

__global__ __launch_bounds__(256) void k_scan3(const int* __restrict__ deg, const int* __restrict__ bsum,
                                               int N, int* __restrict__ rowptr, int* __restrict__ cursor) {
    int i = blockIdx.x * 256 + threadIdx.x;
    if (i == 0) rowptr[0] = 0;
    if (i < N) {
        int inc = rowptr[i + 1] + bsum[blockIdx.x];
        rowptr[i + 1] = inc;
        cursor[i] = inc - deg[i];
    }
}

__global__ __launch_bounds__(256) void k_fill(const int* __restrict__ ei, int E,
                                              const float* __restrict__ dinv, int* __restrict__ cursor,
                                              int* __restrict__ esrc, float* __restrict__ escale) {
    int e = blockIdx.x * 256 + threadIdx.x;
    if (e < E) {
        int s = ei[e], d = ei[E + e];
        int slot = atomicAdd(&cursor[d], 1);
        esrc[slot] = s;
        escale[slot] = dinv[s];
    }
}

// ---------------- weight prep: transpose + bf16 ----------------
// 3x W_gcn [512][512] -> WgcnT[i][n][k]; W_gate [1024][512] -> WgateT[n][k]

__global__ __launch_bounds__(256) void k_wprep(const float* __restrict__ Wg, const float* __restrict__ Wgate,
                                               unsigned short* __restrict__ WgT, unsigned short* __restrict__ WgateT) {
    int id = blockIdx.x * 256 + threadIdx.x;
    if (id < 3 * 512 * 512) {
        int i = id >> 18, rem = id & 262143;
        int n = rem >> 9, k = rem & 511;
        WgT[id] = f2bf(Wg[((size_t)i * 512 + k) * 512 + n]);
    } else {
        int rem = id - 3 * 512 * 512;
        if (rem < 512 * 1024) {
            int n = rem >> 10, k = rem & 1023;
            WgateT[rem] = f2bf(Wgate[(size_t)k * 512 + n]);
        }
    }
}

// ---------------- h_in (fp32) -> bf16 ----------------

__global__ __launch_bounds__(256) void k_hbf(const float* __restrict__ in, unsigned short* __restrict__ out, int total8) {
    int i = blockIdx.x * 256 + threadIdx.x;
    if (i >= total8) return;
    const float4* p = (const float4*)(in + (size_t)i * 8);
    float4 a = p[0], b = p[1];
    uint4 o;
    o.x = (unsigned)f2bf(a.x) | ((unsigned)f2bf(a.y) << 16);
    o.y = (unsigned)f2bf(a.z) | ((unsigned)f2bf(a.w) << 16);
    o.z = (unsigned)f2bf(b.x) | ((unsigned)f2bf(b.y) << 16);
    o.w = (unsigned)f2bf(b.z) | ((unsigned)f2bf(b.w) << 16);
    *(uint4*)(out + (size_t)i * 8) = o;
}

// ---------------- MFMA GEMM: C[M,512] = A[M,K] @ BT[512,K]^T ----------------
// A bf16 (row stride 512; for GATE, k>=512 reads A2), BT bf16 [512][K].
// GATE=0: writes xw bf16. GATE=1: fused sigmoid gate + blend, updates hcur f32 in place + writes hbf_out.

template<int GATE>
__global__ __launch_bounds__(256) void k_mm(const unsigned short* __restrict__ A1,
                                            const unsigned short* __restrict__ A2,
                                            const unsigned short* __restrict__ BT, int K, int M,
                                            unsigned short* __restrict__ xw_out,
                                            const float* __restrict__ bg,
                                            const unsigned short* __restrict__ hn_bf,
                                            float* __restrict__ hcur,
                                            unsigned short* __restrict__ hbf_out) {
    __shared__ unsigned short As[128 * 64];
    __shared__ unsigned short Bs[128 * 64];
    const int tid  = threadIdx.x;
    const int lane = tid & 63;
    const int w    = tid >> 6;
    const int wm   = w >> 1, wn = w & 1;
    const int bm   = blockIdx.x * 128;
    const int bn   = blockIdx.y * 128;

    f32x4 acc[4][4] = {};

    const int sr    = lane >> 3;   // 0..7
    const int sslot = lane & 7;    // 16B slot in row

    for (int k0 = 0; k0 < K; k0 += 64) {
        const unsigned short* Asrc = (GATE && k0 >= 512) ? A2 : A1;
        const int ka = k0 & 511;
        uint4 ra[4], rb[4];
        #pragma unroll
        for (int i = 0; i < 4; ++i) {
            int r = w * 32 + i * 8 + sr;
            ra[i] = *(const uint4*)(Asrc + (size_t)(bm + r) * 512 + ka + sslot * 8);
            rb[i] = *(const uint4*)(BT + (size_t)(bn + r) * K + k0 + sslot * 8);
        }
        __syncthreads();
        int swb = (sslot ^ sr) << 4;     // write swizzle (r&7 == sr)
        #pragma unroll
        for (int i = 0; i < 4; ++i) {
            int r = w * 32 + i * 8 + sr;
            *(uint4*)((char*)As + r * 128 + swb) = ra[i];
            *(uint4*)((char*)Bs + r * 128 + swb) = rb[i];
        }
        __syncthreads();
        #pragma unroll
        for (int kk = 0; kk < 2; ++kk) {
            int slot_sw = ((kk * 4 + (lane >> 4)) ^ (lane & 7)) << 4;
            bf16x8 a[4], b[4];
            #pragma unroll
            for (int mi = 0; mi < 4; ++mi) {
                int rowa = wm * 64 + mi * 16 + (lane & 15);
                a[mi] = *(const bf16x8*)((const char*)As + rowa * 128 + slot_sw);
                int rowb = wn * 64 + mi * 16 + (lane & 15);
                b[mi] = *(const bf16x8*)((const char*)Bs + rowb * 128 + slot_sw);
            }
            #pragma unroll
            for (int mi = 0; mi < 4; ++mi)
                #pragma unroll
                for (int ni = 0; ni < 4; ++ni)
                    acc[mi][ni] = __builtin_amdgcn_mfma_f32_16x16x32_bf16(a[mi], b[ni], acc[mi][ni], 0, 0, 0);
        }
    }

    // epilogue: D[row][col], col = lane&15, row = (lane>>4)*4 + j within 16x16 frag
    #pragma unroll
    for (int mi = 0; mi < 4; ++mi) {
        #pragma unroll
        for (int j = 0; j < 4; ++j) {
            int row = bm + wm * 64 + mi * 16 + (lane >> 4) * 4 + j;
            if (row < M) {
                #pragma unroll
                for (int ni = 0; ni < 4; ++ni) {
                    int col = bn + wn * 64 + ni * 16 + (lane & 15);
                    float v = acc[mi][ni][j];
                    size_t idx = (size_t)row * 512 + col;
                    if (GATE) {
                        float g = 1.0f / (1.0f + __expf(-(v + bg[col])));
                        float hn = bf2f(hn_bf[idx]);
                        float hc = hcur[idx];
                        float o = g * hn + (1.0f - g) * hc;
                        hcur[idx] = o;
                        hbf_out[idx] = f2bf(o);
                    } else {
                        xw_out[idx] = f2bf(v);
                    }
                }
            }
        }
    }
}

// ---------------- fused gather + bias + LayerNorm ----------------
// one wave per dst row; xw is bf16; writes bf16 h (and optionally f32 h)

template<int WF32>
__global__ __launch_bounds__(256) void k_gather(const unsigned short* __restrict__ xw,
                                                const int* __restrict__ rowptr,
                                                const int* __restrict__ esrc, const float* __restrict__ escale,
                                                const float* __restrict__ dinv, const float* __restrict__ bias,
                                                const float* __restrict__ gamma, const float* __restrict__ beta,
                                                float* __restrict__ outf, unsigned short* __restrict__ outb, int N) {
    int wave = threadIdx.x >> 6, lane = threadIdx.x & 63;
    int n = blockIdx.x * 4 + wave;
    if (n >= N) return;
    int beg = rowptr[n], end = rowptr[n + 1];
    int c0 = lane * 8;
    float acc[8] = {};
    for (int j = beg; j < end; ++j) {
        int s = esrc[j];
        float w = escale[j];
        uint4 u = *(const uint4*)(xw + (size_t)s * HID + c0);
        acc[0] = fmaf(w, bf_lo(u.x), acc[0]); acc[1] = fmaf(w, bf_hi(u.x), acc[1]);
        acc[2] = fmaf(w, bf_lo(u.y), acc[2]); acc[3] = fmaf(w, bf_hi(u.y), acc[3]);
        acc[4] = fmaf(w, bf_lo(u.z), acc[4]); acc[5] = fmaf(w, bf_hi(u.z), acc[5]);
        acc[6] = fmaf(w, bf_lo(u.w), acc[6]); acc[7] = fmaf(w, bf_hi(u.w), acc[7]);
    }
    float dn = dinv[n];
    float4 b0 = *(const float4*)&bias[c0];
    float4 b1 = *(const float4*)&bias[c0 + 4];
    float bb[8] = {b0.x, b0.y, b0.z, b0.w, b1.x, b1.y, b1.z, b1.w};
    float v[8];
    #pragma unroll
    for (int j = 0; j < 8; ++j) v[j] = fmaf(acc[j], dn, bb[j]);
    float s1 = 0.f, s2 = 0.f;
    #pragma unroll
    for (int j = 0; j < 8; ++j) { s1 += v[j]; s2 += v[j] * v[j]; }
    #pragma unroll
    for (int m = 1; m < 64; m <<= 1) { s1 += __shfl_xor(s1, m); s2 += __shfl_xor(s2, m); }
    float mu  = s1 * (1.0f / 512.0f);
    float var = fmaxf(s2 * (1.0f / 512.0f) - mu * mu, 0.0f);
    float r   = rsqrtf(var + 1e-5f);
    float4 g0 = *(const float4*)&gamma[c0];
    float4 g1 = *(const float4*)&gamma[c0 + 4];
    float4 e0 = *(const float4*)&beta[c0];
    float4 e1 = *(const float4*)&beta[c0 + 4];
    float g[8]  = {g0.x, g0.y, g0.z, g0.w, g1.x, g1.y, g1.z, g1.w};
    float bt[8] = {e0.x, e0.y, e0.z, e0.w, e1.x, e1.y, e1.z, e1.w};
    float o[8];
    #pragma unroll
    for (int j = 0; j < 8; ++j) o[j] = (v[j] - mu) * r * g[j] + bt[j];
    uint4 ob;
    ob.x = (unsigned)f2bf(o[0]) | ((unsigned)f2bf(o[1]) << 16);
    ob.y = (unsigned)f2bf(o[2]) | ((unsigned)f2bf(o[3]) << 16);
    ob.z = (unsigned)f2bf(o[4]) | ((unsigned)f2bf(o[5]) << 16);
    ob.w = (unsigned)f2bf(o[6]) | ((unsigned)f2bf(o[7]) << 16);
    *(uint4*)(outb + (size_t)n * HID + c0) = ob;
    if (WF32) {
        float* xr = outf + (size_t)n * HID;
        float4 q0 = {o[0], o[1], o[2], o[3]}, q1 = {o[4], o[5], o[6], o[7]};
        *(float4*)&xr[c0]     = q0;
        *(float4*)&xr[c0 + 4] = q1;
    }
}

// ---------------- final: out = tanh(hc) + rw * h_orig ----------------

__global__ __launch_bounds__(256) void k_final(const float* __restrict__ hc, const float* __restrict__ h0,
                                               const float* __restrict__ rw_p, float* __restrict__ out, int total4) {
    int i = blockIdx.x * 256 + threadIdx.x;
    if (i >= total4) return;
    float rw = *rw_p;
    float4 h = ((const float4*)hc)[i];
    float4 o = ((const float4*)h0)[i];
    float4 r;
    r.x = tanhf(h.x) + rw * o.x;
    r.y = tanhf(h.y) + rw * o.y;
    r.z = tanhf(h.z) + rw * o.z;
    r.w = tanhf(h.w) + rw * o.w;
    ((float4*)out)[i] = r;
}

// ---------------- launch ----------------

extern "C" void kernel_launch(void* const* d_in, const int* in_sizes, int n_in,
                              void* d_out, int out_size, void* d_ws, size_t ws_size,
                              hipStream_t stream) {
    const float* h_in   = (const float*)d_in[1];
    const int*   ei     = (const int*)d_in[2];
    const float* W_gcn  = (const float*)d_in[3];
    const float* b_gcn  = (const float*)d_in[4];
    const float* ln_g   = (const float*)d_in[5];
    const float* ln_b   = (const float*)d_in[6];
    const float* W_gate = (const float*)d_in[7];
    const float* b_gate = (const float*)d_in[8];
    const float* rw     = (const float*)d_in[9];
    int N = in_sizes[1] / HID;
    int E = in_sizes[2] / 2;
    float* out = (float*)d_out;

    int MB_ = (N + 127) / 128;
    int MP  = MB_ * 128;                       // padded rows for GEMM A staging

    char* ws = (char*)d_ws;
    size_t off = 0;
    auto alloc = [&](size_t bytes) { void* p = ws + off; off += (bytes + 255) & ~(size_t)255; return p; };
    size_t nbh = (size_t)MP * HID * 2;         // bf16 node buffer
    unsigned short* xw    = (unsigned short*)alloc(nbh);
    unsigned short* hbf0  = (unsigned short*)alloc(nbh);
    unsigned short* hbf1  = (unsigned short*)alloc(nbh);
    unsigned short* hbf2  = (unsigned short*)alloc(nbh);
    float*          hcur  = (float*)alloc((size_t)N * HID * 4);
    unsigned short* WgT   = (unsigned short*)alloc((size_t)3 * 512 * 512 * 2);
    unsigned short* WgateT= (unsigned short*)alloc((size_t)512 * 1024 * 2);
    int*   deg    = (int*)  alloc((size_t)N * 4);
    float* dinv   = (float*)alloc((size_t)N * 4);
    int*   rowptr = (int*)  alloc((size_t)(N + 1) * 4);
    int*   cursor = (int*)  alloc((size_t)N * 4);
    int*   bsum   = (int*)  alloc(1024);
    int*   esrc   = (int*)  alloc((size_t)E * 4);
    float* escale = (float*)alloc((size_t)E * 4);

    int NB = (N + 255) / 256;

    // CSR build
    hipMemsetAsync(deg, 0, (size_t)N * 4, stream);
    k_deg  <<<(E + 255) / 256, 256, 0, stream>>>(ei, E, deg);
    k_dinv <<<NB, 256, 0, stream>>>(deg, dinv, N);
    k_scan1<<<NB, 256, 0, stream>>>(deg, N, rowptr, bsum);
    k_scan2<<<1,  256, 0, stream>>>(bsum, NB);
    k_scan3<<<NB, 256, 0, stream>>>(deg, bsum, N, rowptr, cursor);
    k_fill <<<(E + 255) / 256, 256, 0, stream>>>(ei, E, dinv, cursor, esrc, escale);

    // weight prep + h_in -> bf16
    k_wprep<<<(3 * 512 * 512 + 512 * 1024 + 255) / 256, 256, 0, stream>>>(W_gcn, W_gate, WgT, WgateT);
    k_hbf<<<(N * HID / 8 + 255) / 256, 256, 0, stream>>>(h_in, hbf0, N * HID / 8);

    dim3 gg(MB_, 4);
    int total4 = N * HID / 4;
    int NG = (N + 3) / 4;

    // layer 0
    k_mm<0><<<gg, 256, 0, stream>>>(hbf0, nullptr, WgT, 512, N, xw, nullptr, nullptr, nullptr, nullptr);
    k_gather<1><<<NG, 256, 0, stream>>>(xw, rowptr, esrc, escale, dinv, b_gcn, ln_g, ln_b, hcur, hbf1, N);

    // layer 1: gcn -> gather -> fused gate(K=1024)
    k_mm<0><<<gg, 256, 0, stream>>>(hbf1, nullptr, WgT + (size_t)1 * 512 * 512, 512, N, xw, nullptr, nullptr, nullptr, nullptr);
    k_gather<0><<<NG, 256, 0, stream>>>(xw, rowptr, esrc, escale, dinv, b_gcn + 512, ln_g + 512, ln_b + 512, nullptr, hbf2, N);
    k_mm<1><<<gg, 256, 0, stream>>>(hbf1, hbf2, WgateT, 1024, N, nullptr, b_gate, hbf2, hcur, hbf0);

    // layer 2
    k_mm<0><<<gg, 256, 0, stream>>>(hbf0, nullptr, WgT + (size_t)2 * 512 * 512, 512, N, xw, nullptr, nullptr, nullptr, nullptr);
    k_gather<0><<<NG, 256, 0, stream>>>(xw, rowptr, esrc, escale, dinv, b_gcn + 1024, ln_g + 1024, ln_b + 1024, nullptr, hbf1, N);
    k_mm<1><<<gg, 256, 0, stream>>>(hbf0, hbf1, WgateT, 1024, N, nullptr, b_gate, hbf1, hcur, hbf2);

    // final
    k_final<<<(total4 + 255) / 256, 256, 0, stream>>>(hcur, h_in, rw, out, total4);
}

// Round 5
// 1321.811 us; speedup vs baseline: 4.3553x; 1.0596x over previous
//
#include <hip/hip_runtime.h>
#include <hip/hip_bf16.h>

#define HID 512

typedef __attribute__((ext_vector_type(8))) short bf16x8;
typedef __attribute__((ext_vector_type(4))) float f32x4;

__device__ inline unsigned short f2bf(float x) {
    __hip_bfloat16 b = __float2bfloat16(x);
    return *reinterpret_cast<unsigned short*>(&b);
}
__device__ inline float bf_lo(unsigned int u) { return __uint_as_float(u << 16); }
__device__ inline float bf_hi(unsigned int u) { return __uint_as_float(u & 0xffff0000u); }
__device__ inline unsigned int pk2(float a, float b) {
    return (unsigned)f2bf(a) | ((unsigned)f2bf(b) << 16);
}

// ---------------- degree / CSR build ----------------

__global__ __launch_bounds__(256) void k_deg(const int* __restrict__ ei, int E, int* __restrict__ deg) {
    int e = blockIdx.x * 256 + threadIdx.x;
    if (e < E) atomicAdd(&deg[ei[E + e]], 1);
}

__global__ __launch_bounds__(256) void k_dinv(const int* __restrict__ deg, float* __restrict__ dinv, int N) {
    int n = blockIdx.x * 256 + threadIdx.x;
    if (n < N) {
        int c = deg[n];
        dinv[n] = (c > 0) ? rsqrtf((float)c) : 0.0f;
    }
}

__global__ __launch_bounds__(256) void k_scan1(const int* __restrict__ deg, int N,
                                               int* __restrict__ rowptr, int* __restrict__ bsum) {
    int i = blockIdx.x * 256 + threadIdx.x;
    int v = (i < N) ? deg[i] : 0;
    int lane = threadIdx.x & 63, w = threadIdx.x >> 6;
    int s = v;
    #pragma unroll
    for (int m = 1; m < 64; m <<= 1) { int t = __shfl_up(s, m); if (lane >= m) s += t; }
    __shared__ int wsum[4];
    if (lane == 63) wsum[w] = s;
    __syncthreads();
    #pragma unroll
    for (int j = 0; j < 4; ++j) if (j < w) s += wsum[j];
    if (i < N) rowptr[i + 1] = s;
    if (threadIdx.x == 255) bsum[blockIdx.x] = s;
}

__global__ __launch_bounds__(256) void k_scan2(int* __restrict__ bsum, int nb) {
    int tid = threadIdx.x;
    int v = (tid < nb) ? bsum[tid] : 0;
    int lane = tid & 63, w = tid >> 6;
    int s = v;
    #pragma unroll
    for (int m = 1; m < 64; m <<= 1) { int t = __shfl_up(s, m); if (lane >= m) s += t; }
    __shared__ int wsum[4];
    if (lane == 63) wsum[w] = s;
    __syncthreads();
    #pragma unroll
    for (int j = 0; j < 4; ++j) if (j < w) s += wsum[j];
    if (tid < nb) bsum[tid] = s - v;
}

__global__ __launch_bounds__(256) void k_scan3(const int* __restrict__ deg, const int* __restrict__ bsum,
                                               int N, int* __restrict__ rowptr, int* __restrict__ cursor) {
    int i = blockIdx.x * 256 + threadIdx.x;
    if (i == 0) rowptr[0] = 0;
    if (i < N) {
        int inc = rowptr[i + 1] + bsum[blockIdx.x];
        rowptr[i + 1] = inc;
        cursor[i] = inc - deg[i];
    }
}

__global__ __launch_bounds__(256) void k_fill(const int* __restrict__ ei, int E,
                                              const float* __restrict__ dinv, int* __restrict__ cursor,
                                              int* __restrict__ esrc, float* __restrict__ escale) {
    int e = blockIdx.x * 256 + threadIdx.x;
    if (e < E) {
        int s = ei[e], d = ei[E + e];
        int slot = atomicAdd(&cursor[d], 1);
        esrc[slot] = s;
        escale[slot] = dinv[s];
    }
}

// ---------------- weight prep: transpose + bf16 ----------------

__global__ __launch_bounds__(256) void k_wprep(const float* __restrict__ Wg, const float* __restrict__ Wgate,
                                               unsigned short* __restrict__ WgT, unsigned short* __restrict__ WgateT) {
    int id = blockIdx.x * 256 + threadIdx.x;
    if (id < 3 * 512 * 512) {
        int i = id >> 18, rem = id & 262143;
        int n = rem >> 9, k = rem & 511;
        WgT[id] = f2bf(Wg[((size_t)i * 512 + k) * 512 + n]);
    } else {
        int rem = id - 3 * 512 * 512;
        if (rem < 512 * 1024) {
            int n = rem >> 10, k = rem & 1023;
            WgateT[rem] = f2bf(Wgate[(size_t)k * 512 + n]);
        }
    }
}

// ---------------- h_in (fp32) -> bf16 ----------------

__global__ __launch_bounds__(256) void k_hbf(const float* __restrict__ in, unsigned short* __restrict__ out, int total8) {
    int i = blockIdx.x * 256 + threadIdx.x;
    if (i >= total8) return;
    const float4* p = (const float4*)(in + (size_t)i * 8);
    float4 a = p[0], b = p[1];
    uint4 o;
    o.x = pk2(a.x, a.y);
    o.y = pk2(a.z, a.w);
    o.z = pk2(b.x, b.y);
    o.w = pk2(b.z, b.w);
    *(uint4*)(out + (size_t)i * 8) = o;
}

// ---------------- MFMA GEMM: C[M,512] = A[M,K] @ BT[512,K]^T ----------------
// MODE 0: write xw bf16. MODE 1: fused sigmoid gate + blend -> hcur f32 + hbf bf16.
// MODE 2: gate + blend + tanh + residual -> outp f32 (final output).

template<int MODE>
__global__ __launch_bounds__(256) void k_mm(const unsigned short* __restrict__ A1,
                                            const unsigned short* __restrict__ A2,
                                            const unsigned short* __restrict__ BT, int K, int M,
                                            unsigned short* __restrict__ xw_out,
                                            const float* __restrict__ bg,
                                            const unsigned short* __restrict__ hn_bf,
                                            float* __restrict__ hcur,
                                            unsigned short* __restrict__ hbf_out,
                                            const float* __restrict__ h0,
                                            const float* __restrict__ rw_p,
                                            float* __restrict__ outp) {
    __shared__ char smem[32768];
    unsigned short* As = (unsigned short*)smem;
    unsigned short* Bs = (unsigned short*)(smem + 16384);

    const int tid  = threadIdx.x;
    const int lane = tid & 63;
    const int w    = tid >> 6;
    const int wm   = w >> 1, wn = w & 1;
    const int bm   = blockIdx.x * 128;
    const int bn   = blockIdx.y * 128;

    f32x4 acc[4][4] = {};

    const int sr    = lane >> 3;   // 0..7
    const int sslot = lane & 7;    // 16B slot in row

    uint4 ra[4], rb[4];
    auto load_tile = [&](int k0) {
        const unsigned short* Asrc = (MODE && k0 >= 512) ? A2 : A1;
        const int ka = k0 & 511;
        #pragma unroll
        for (int i = 0; i < 4; ++i) {
            int r = w * 32 + i * 8 + sr;
            ra[i] = *(const uint4*)(Asrc + (size_t)(bm + r) * 512 + ka + sslot * 8);
            rb[i] = *(const uint4*)(BT + (size_t)(bn + r) * K + k0 + sslot * 8);
        }
    };

    load_tile(0);
    for (int k0 = 0;;) {
        __syncthreads();
        int swb = (sslot ^ sr) << 4;     // write swizzle (r&7 == sr)
        #pragma unroll
        for (int i = 0; i < 4; ++i) {
            int r = w * 32 + i * 8 + sr;
            *(uint4*)((char*)As + r * 128 + swb) = ra[i];
            *(uint4*)((char*)Bs + r * 128 + swb) = rb[i];
        }
        __syncthreads();
        int kn = k0 + 64;
        if (kn < K) load_tile(kn);       // prefetch next tile under the MFMAs
        #pragma unroll
        for (int kk = 0; kk < 2; ++kk) {
            int slot_sw = ((kk * 4 + (lane >> 4)) ^ (lane & 7)) << 4;
            bf16x8 a[4], b[4];
            #pragma unroll
            for (int mi = 0; mi < 4; ++mi) {
                int rowa = wm * 64 + mi * 16 + (lane & 15);
                a[mi] = *(const bf16x8*)((const char*)As + rowa * 128 + slot_sw);
                int rowb = wn * 64 + mi * 16 + (lane & 15);
                b[mi] = *(const bf16x8*)((const char*)Bs + rowb * 128 + slot_sw);
            }
            #pragma unroll
            for (int mi = 0; mi < 4; ++mi)
                #pragma unroll
                for (int ni = 0; ni < 4; ++ni)
                    acc[mi][ni] = __builtin_amdgcn_mfma_f32_16x16x32_bf16(a[mi], b[ni], acc[mi][ni], 0, 0, 0);
        }
        if (kn >= K) break;
        k0 = kn;
    }

    // ---- coalesced epilogue via per-wave LDS transpose ----
    __syncthreads();
    float* cs = (float*)(smem + w * 4352);   // 16 rows x stride 68 f32
    const int rr = lane >> 2;                 // 0..15: row within 16-row slab
    const int cc = (lane & 3) << 4;           // 0/16/32/48: 16-col chunk
    const int wrow = (lane >> 4) * 4;
    const int wcol = lane & 15;
    float rwv = (MODE == 2) ? *rw_p : 0.0f;

    #pragma unroll
    for (int mi = 0; mi < 4; ++mi) {
        #pragma unroll
        for (int ni = 0; ni < 4; ++ni)
            #pragma unroll
            for (int j = 0; j < 4; ++j)
                cs[(wrow + j) * 68 + ni * 16 + wcol] = acc[mi][ni][j];
        // same-wave write->read; lgkmcnt ordering, no barrier needed
        float v[16];
        #pragma unroll
        for (int t = 0; t < 4; ++t) {
            float4 q = *(const float4*)&cs[rr * 68 + cc + t * 4];
            v[t * 4 + 0] = q.x; v[t * 4 + 1] = q.y; v[t * 4 + 2] = q.z; v[t * 4 + 3] = q.w;
        }
        int row = bm + wm * 64 + mi * 16 + rr;
        int col = bn + wn * 64 + cc;
        if (row < M) {
            size_t base = (size_t)row * 512 + col;
            if (MODE == 0) {
                uint4 o0, o1;
                o0.x = pk2(v[0], v[1]);  o0.y = pk2(v[2], v[3]);
                o0.z = pk2(v[4], v[5]);  o0.w = pk2(v[6], v[7]);
                o1.x = pk2(v[8], v[9]);  o1.y = pk2(v[10], v[11]);
                o1.z = pk2(v[12], v[13]); o1.w = pk2(v[14], v[15]);
                *(uint4*)(xw_out + base)     = o0;
                *(uint4*)(xw_out + base + 8) = o1;
            } else {
                float bgv[16], hcv[16], hnv[16];
                #pragma unroll
                for (int t = 0; t < 4; ++t) {
                    float4 bq = *(const float4*)&bg[col + t * 4];
                    bgv[t*4+0] = bq.x; bgv[t*4+1] = bq.y; bgv[t*4+2] = bq.z; bgv[t*4+3] = bq.w;
                    float4 hq = *(const float4*)&hcur[base + t * 4];
                    hcv[t*4+0] = hq.x; hcv[t*4+1] = hq.y; hcv[t*4+2] = hq.z; hcv[t*4+3] = hq.w;
                }
                uint4 hn0 = *(const uint4*)(hn_bf + base);
                uint4 hn1 = *(const uint4*)(hn_bf + base + 8);
                hnv[0] = bf_lo(hn0.x); hnv[1] = bf_hi(hn0.x); hnv[2] = bf_lo(hn0.y); hnv[3] = bf_hi(hn0.y);
                hnv[4] = bf_lo(hn0.z); hnv[5] = bf_hi(hn0.z); hnv[6] = bf_lo(hn0.w); hnv[7] = bf_hi(hn0.w);
                hnv[8] = bf_lo(hn1.x); hnv[9] = bf_hi(hn1.x); hnv[10] = bf_lo(hn1.y); hnv[11] = bf_hi(hn1.y);
                hnv[12] = bf_lo(hn1.z); hnv[13] = bf_hi(hn1.z); hnv[14] = bf_lo(hn1.w); hnv[15] = bf_hi(hn1.w);
                float o[16];
                #pragma unroll
                for (int i = 0; i < 16; ++i) {
                    float g = 1.0f / (1.0f + __expf(-(v[i] + bgv[i])));
                    o[i] = g * hnv[i] + (1.0f - g) * hcv[i];
                }
                if (MODE == 1) {
                    #pragma unroll
                    for (int t = 0; t < 4; ++t) {
                        float4 q = {o[t*4+0], o[t*4+1], o[t*4+2], o[t*4+3]};
                        *(float4*)&hcur[base + t * 4] = q;
                    }
                    uint4 o0, o1;
                    o0.x = pk2(o[0], o[1]);  o0.y = pk2(o[2], o[3]);
                    o0.z = pk2(o[4], o[5]);  o0.w = pk2(o[6], o[7]);
                    o1.x = pk2(o[8], o[9]);  o1.y = pk2(o[10], o[11]);
                    o1.z = pk2(o[12], o[13]); o1.w = pk2(o[14], o[15]);
                    *(uint4*)(hbf_out + base)     = o0;
                    *(uint4*)(hbf_out + base + 8) = o1;
                } else {
                    #pragma unroll
                    for (int t = 0; t < 4; ++t) {
                        float4 hv = *(const float4*)&h0[base + t * 4];
                        float4 q;
                        q.x = tanhf(o[t*4+0]) + rwv * hv.x;
                        q.y = tanhf(o[t*4+1]) + rwv * hv.y;
                        q.z = tanhf(o[t*4+2]) + rwv * hv.z;
                        q.w = tanhf(o[t*4+3]) + rwv * hv.w;
                        *(float4*)&outp[base + t * 4] = q;
                    }
                }
            }
        }
    }
}

// ---------------- fused gather + bias + LayerNorm ----------------

template<int WF32>
__global__ __launch_bounds__(256) void k_gather(const unsigned short* __restrict__ xw,
                                                const int* __restrict__ rowptr,
                                                const int* __restrict__ esrc, const float* __restrict__ escale,
                                                const float* __restrict__ dinv, const float* __restrict__ bias,
                                                const float* __restrict__ gamma, const float* __restrict__ beta,
                                                float* __restrict__ outf, unsigned short* __restrict__ outb, int N) {
    int wave = threadIdx.x >> 6, lane = threadIdx.x & 63;
    int n = blockIdx.x * 4 + wave;
    if (n >= N) return;
    int beg = rowptr[n], end = rowptr[n + 1];
    int c0 = lane * 8;
    float acc[8] = {};
    for (int j = beg; j < end; ++j) {
        int s = esrc[j];
        float w = escale[j];
        uint4 u = *(const uint4*)(xw + (size_t)s * HID + c0);
        acc[0] = fmaf(w, bf_lo(u.x), acc[0]); acc[1] = fmaf(w, bf_hi(u.x), acc[1]);
        acc[2] = fmaf(w, bf_lo(u.y), acc[2]); acc[3] = fmaf(w, bf_hi(u.y), acc[3]);
        acc[4] = fmaf(w, bf_lo(u.z), acc[4]); acc[5] = fmaf(w, bf_hi(u.z), acc[5]);
        acc[6] = fmaf(w, bf_lo(u.w), acc[6]); acc[7] = fmaf(w, bf_hi(u.w), acc[7]);
    }
    float dn = dinv[n];
    float4 b0 = *(const float4*)&bias[c0];
    float4 b1 = *(const float4*)&bias[c0 + 4];
    float bb[8] = {b0.x, b0.y, b0.z, b0.w, b1.x, b1.y, b1.z, b1.w};
    float v[8];
    #pragma unroll
    for (int j = 0; j < 8; ++j) v[j] = fmaf(acc[j], dn, bb[j]);
    float s1 = 0.f, s2 = 0.f;
    #pragma unroll
    for (int j = 0; j < 8; ++j) { s1 += v[j]; s2 += v[j] * v[j]; }
    #pragma unroll
    for (int m = 1; m < 64; m <<= 1) { s1 += __shfl_xor(s1, m); s2 += __shfl_xor(s2, m); }
    float mu  = s1 * (1.0f / 512.0f);
    float var = fmaxf(s2 * (1.0f / 512.0f) - mu * mu, 0.0f);
    float r   = rsqrtf(var + 1e-5f);
    float4 g0 = *(const float4*)&gamma[c0];
    float4 g1 = *(const float4*)&gamma[c0 + 4];
    float4 e0 = *(const float4*)&beta[c0];
    float4 e1 = *(const float4*)&beta[c0 + 4];
    float g[8]  = {g0.x, g0.y, g0.z, g0.w, g1.x, g1.y, g1.z, g1.w};
    float bt[8] = {e0.x, e0.y, e0.z, e0.w, e1.x, e1.y, e1.z, e1.w};
    float o[8];
    #pragma unroll
    for (int j = 0; j < 8; ++j) o[j] = (v[j] - mu) * r * g[j] + bt[j];
    uint4 ob;
    ob.x = pk2(o[0], o[1]);
    ob.y = pk2(o[2], o[3]);
    ob.z = pk2(o[4], o[5]);
    ob.w = pk2(o[6], o[7]);
    *(uint4*)(outb + (size_t)n * HID + c0) = ob;
    if (WF32) {
        float* xr = outf + (size_t)n * HID;
        float4 q0 = {o[0], o[1], o[2], o[3]}, q1 = {o[4], o[5], o[6], o[7]};
        *(float4*)&xr[c0]     = q0;
        *(float4*)&xr[c0 + 4] = q1;
    }
}

// ---------------- launch ----------------

extern "C" void kernel_launch(void* const* d_in, const int* in_sizes, int n_in,
                              void* d_out, int out_size, void* d_ws, size_t ws_size,
                              hipStream_t stream) {
    const float* h_in   = (const float*)d_in[1];
    const int*   ei     = (const int*)d_in[2];
    const float* W_gcn  = (const float*)d_in[3];
    const float* b_gcn  = (const float*)d_in[4];
    const float* ln_g   = (const float*)d_in[5];
    const float* ln_b   = (const float*)d_in[6];
    const float* W_gate = (const float*)d_in[7];
    const float* b_gate = (const float*)d_in[8];
    const float* rw     = (const float*)d_in[9];
    int N = in_sizes[1] / HID;
    int E = in_sizes[2] / 2;
    float* out = (float*)d_out;

    int MB_ = (N + 127) / 128;
    int MP  = MB_ * 128;

    char* ws = (char*)d_ws;
    size_t off = 0;
    auto alloc = [&](size_t bytes) { void* p = ws + off; off += (bytes + 255) & ~(size_t)255; return p; };
    size_t nbh = (size_t)MP * HID * 2;
    unsigned short* xw    = (unsigned short*)alloc(nbh);
    unsigned short* hbf0  = (unsigned short*)alloc(nbh);
    unsigned short* hbf1  = (unsigned short*)alloc(nbh);
    unsigned short* hbf2  = (unsigned short*)alloc(nbh);
    float*          hcur  = (float*)alloc((size_t)N * HID * 4);
    unsigned short* WgT   = (unsigned short*)alloc((size_t)3 * 512 * 512 * 2);
    unsigned short* WgateT= (unsigned short*)alloc((size_t)512 * 1024 * 2);
    int*   deg    = (int*)  alloc((size_t)N * 4);
    float* dinv   = (float*)alloc((size_t)N * 4);
    int*   rowptr = (int*)  alloc((size_t)(N + 1) * 4);
    int*   cursor = (int*)  alloc((size_t)N * 4);
    int*   bsum   = (int*)  alloc(1024);
    int*   esrc   = (int*)  alloc((size_t)E * 4);
    float* escale = (float*)alloc((size_t)E * 4);

    int NB = (N + 255) / 256;

    // CSR build
    hipMemsetAsync(deg, 0, (size_t)N * 4, stream);
    k_deg  <<<(E + 255) / 256, 256, 0, stream>>>(ei, E, deg);
    k_dinv <<<NB, 256, 0, stream>>>(deg, dinv, N);
    k_scan1<<<NB, 256, 0, stream>>>(deg, N, rowptr, bsum);
    k_scan2<<<1,  256, 0, stream>>>(bsum, NB);
    k_scan3<<<NB, 256, 0, stream>>>(deg, bsum, N, rowptr, cursor);
    k_fill <<<(E + 255) / 256, 256, 0, stream>>>(ei, E, dinv, cursor, esrc, escale);

    // weight prep + h_in -> bf16
    k_wprep<<<(3 * 512 * 512 + 512 * 1024 + 255) / 256, 256, 0, stream>>>(W_gcn, W_gate, WgT, WgateT);
    k_hbf<<<(N * HID / 8 + 255) / 256, 256, 0, stream>>>(h_in, hbf0, N * HID / 8);

    dim3 gg(MB_, 4);
    int NG = (N + 3) / 4;

    // layer 0
    k_mm<0><<<gg, 256, 0, stream>>>(hbf0, nullptr, WgT, 512, N, xw,
                                    nullptr, nullptr, nullptr, nullptr, nullptr, nullptr, nullptr);
    k_gather<1><<<NG, 256, 0, stream>>>(xw, rowptr, esrc, escale, dinv, b_gcn, ln_g, ln_b, hcur, hbf1, N);

    // layer 1: gcn -> gather -> fused gate(K=1024) -> hcur/hbf0
    k_mm<0><<<gg, 256, 0, stream>>>(hbf1, nullptr, WgT + (size_t)1 * 512 * 512, 512, N, xw,
                                    nullptr, nullptr, nullptr, nullptr, nullptr, nullptr, nullptr);
    k_gather<0><<<NG, 256, 0, stream>>>(xw, rowptr, esrc, escale, dinv,
                                        b_gcn + 512, ln_g + 512, ln_b + 512, nullptr, hbf2, N);
    k_mm<1><<<gg, 256, 0, stream>>>(hbf1, hbf2, WgateT, 1024, N, nullptr,
                                    b_gate, hbf2, hcur, hbf0, nullptr, nullptr, nullptr);

    // layer 2: gcn -> gather -> fused gate + tanh + residual -> out
    k_mm<0><<<gg, 256, 0, stream>>>(hbf0, nullptr, WgT + (size_t)2 * 512 * 512, 512, N, xw,
                                    nullptr, nullptr, nullptr, nullptr, nullptr, nullptr, nullptr);
    k_gather<0><<<NG, 256, 0, stream>>>(xw, rowptr, esrc, escale, dinv,
                                        b_gcn + 1024, ln_g + 1024, ln_b + 1024, nullptr, hbf1, N);
    k_mm<2><<<gg, 256, 0, stream>>>(hbf0, hbf1, WgateT, 1024, N, nullptr,
                                    b_gate, hbf1, hcur, nullptr, h_in, rw, out);
}